// Round 6
// baseline (78493.567 us; speedup 1.0000x reference)
//
#include <hip/hip_runtime.h>
#include <math.h>

// ESN forward: x_{t+1} = 0.1*x_t + 0.9*tanh(W_in @ u_t + W @ x_t); y_t = Wout @ x_{t+1}
// W sparse (5%) -> padded ELL in ws. 64 cooperative WGs x 512, fence-free.
// R6: single-round-trip tagged-data exchange with BOUNDED polling:
//   - wave 0 polls 64 sentinel words (one per writer WG); waves 1-7 park at barrier
//   - then ONE bulk tagged load (8 coalesced u64/thread) + selective retry (rare)
//   - ELL slice register-prefetched during the wait window (x-independent)
//   - per-row immediate publish (no pre-publish barrier)

#define NX 4096
#define NU 128
#define NY 64
#define TSTEPS 4096
#define CAP 352            // padded nnz per row (mean 204.8, sd 13.9)
#define WGS 64
#define TPB 512
#define RPW (NX / WGS)     // 64 rows per workgroup
#define TPR (TPB / RPW)    // 8 threads per row
#define EPT (CAP / TPR)    // 44 ELL entries per thread -> 22 int4
#define UPT (NU / TPR)     // 16 W_in entries per thread
#define XW  (NX / TPB)     // 8 packed words per thread

typedef unsigned long long u64;

// --- Kernel 1: deterministic dense->ELL compaction, one block per row ---
__global__ void build_ell_kernel(const float* __restrict__ W, int2* __restrict__ ell) {
    const int r = blockIdx.x;
    const int tid = threadIdx.x;
    const int wv = tid >> 6, ln = tid & 63;
    __shared__ int wave_tot[4];
    __shared__ int base;
    if (tid == 0) base = 0;
    __syncthreads();
    const float* row = W + (size_t)r * NX;
    int2* out = ell + (size_t)r * CAP;
    for (int chunk = 0; chunk < NX; chunk += 256) {
        float w = row[chunk + tid];
        bool p = (w != 0.0f);
        unsigned long long m = __ballot(p);
        int lp = (int)__popcll(m & ((1ull << ln) - 1ull));
        if (ln == 63) wave_tot[wv] = lp + (p ? 1 : 0);
        __syncthreads();
        int wbase = 0;
        #pragma unroll
        for (int i = 0; i < 4; ++i)
            if (i < wv) wbase += wave_tot[i];
        int tot = wave_tot[0] + wave_tot[1] + wave_tot[2] + wave_tot[3];
        if (p) {
            int o = base + wbase + lp;
            if (o < CAP) out[o] = make_int2(chunk + tid, __float_as_int(w));
        }
        __syncthreads();
        if (tid == 0) base += tot;
        __syncthreads();
    }
    for (int o = base + tid; o < CAP; o += 256) out[o] = make_int2(0, 0);
}

__device__ __forceinline__ u64 ld_agent(const u64* p) {
    return __hip_atomic_load(p, __ATOMIC_RELAXED, __HIP_MEMORY_SCOPE_AGENT);
}

// stage tagged state (epoch `ep`, buffer xs) into LDS xc
__device__ __forceinline__ void stage_state(const u64* xs, float* xc,
                                            int tid, unsigned ep) {
    // wave 0: 64 lanes poll one sentinel each (writer lane's last row word)
    if (tid < 64) {
        const u64* sp = xs + (size_t)tid * RPW + (RPW - 1);
        while ((unsigned)(ld_agent(sp) >> 32) != ep) { }
    }
    __syncthreads();   // release the other 7 waves
    // one-shot bulk load, coalesced; selective retry for rare stragglers
    u64 v[XW];
    #pragma unroll
    for (int j = 0; j < XW; ++j)
        v[j] = ld_agent(xs + tid + TPB * j);
    unsigned miss = 0;
    #pragma unroll
    for (int j = 0; j < XW; ++j)
        if ((unsigned)(v[j] >> 32) != ep) miss |= 1u << j;
    while (miss) {
        __builtin_amdgcn_s_sleep(1);
        #pragma unroll
        for (int j = 0; j < XW; ++j)
            if (miss & (1u << j)) {
                v[j] = ld_agent(xs + tid + TPB * j);
                if ((unsigned)(v[j] >> 32) == ep) miss &= ~(1u << j);
            }
    }
    #pragma unroll
    for (int j = 0; j < XW; ++j)
        xc[tid + TPB * j] = __uint_as_float((unsigned)v[j]);
    __syncthreads();
}

// --- Kernel 2: cooperative sequential recurrence ---
__global__ void __launch_bounds__(TPB, 1) esn_kernel(
    const float* __restrict__ UT, const float* __restrict__ x0,
    const float* __restrict__ Win, const float* __restrict__ Wout,
    const int2* __restrict__ ell, u64* __restrict__ xbuf,  // [2][NX] packed
    float* __restrict__ Y)
{
    __shared__ __align__(16) float xl[2][NX];
    __shared__ float red[TPB / 64];

    const int tid = threadIdx.x;
    const int wg  = blockIdx.x;              // 0..63 (== NY readout rows)
    const int grp = tid >> 3;                // row group within WG (0..63)
    const int ln  = tid & 7;                 // lane within row group
    const int r   = wg * RPW + grp;          // global row this 8-thread group owns

    const float4* winrow = (const float4*)(Win + (size_t)r * NU + ln * UPT);
    const int4*   ellrow = (const int4*)  (ell + (size_t)r * CAP + ln * EPT);
    const float*  woutrow = Wout + (size_t)wg * NX;

    for (int t = 0; t < TSTEPS; ++t) {
        float* xc = xl[t & 1];

        // ---- x-independent: acc = Win[r,:] @ u_t ----
        float acc = 0.0f;
        {
            const float4* u4 = (const float4*)(UT + (size_t)t * NU + ln * UPT);
            #pragma unroll
            for (int i = 0; i < UPT / 4; ++i) {
                float4 w = winrow[i], u = u4[i];
                acc += w.x * u.x + w.y * u.y + w.z * u.z + w.w * u.w;
            }
        }

        // ---- ELL register prefetch (x-independent; overlaps the wait) ----
        int4 e[EPT / 2];
        #pragma unroll
        for (int i = 0; i < EPT / 2; ++i) e[i] = ellrow[i];

        // ---- stage x_t into LDS ----
        if (t == 0) {
            const float4* xs4 = (const float4*)x0;
            float4* xl4 = (float4*)xc;
            #pragma unroll
            for (int i = tid; i < NX / 4; i += TPB) xl4[i] = xs4[i];
            __syncthreads();
        } else {
            stage_state(xbuf + (size_t)(t & 1) * NX, xc, tid, (unsigned)t);
        }

        // ---- acc += W[r,:] @ x_t (gather from LDS, ELL already in regs) ----
        #pragma unroll 4
        for (int i = 0; i < EPT / 2; ++i) {
            int4 cv = e[i];   // two (col,val) pairs
            acc += __int_as_float(cv.y) * xc[cv.x]
                 + __int_as_float(cv.w) * xc[cv.z];
        }
        acc += __shfl_down(acc, 4, 8);
        acc += __shfl_down(acc, 2, 8);
        acc += __shfl_down(acc, 1, 8);
        if (ln == 0) {
            float xn = 0.1f * xc[r] + 0.9f * tanhf(acc);
            u64 packed = ((u64)(unsigned)(t + 1) << 32) | (u64)__float_as_uint(xn);
            __hip_atomic_store(xbuf + (size_t)((t + 1) & 1) * NX + r, packed,
                               __ATOMIC_RELAXED, __HIP_MEMORY_SCOPE_AGENT);
        }

        // ---- readout Y[t-1] = Wout[wg] . x_t (after publish; hidden in wait) ----
        if (t > 0) {
            float a = 0.0f;
            for (int i = tid; i < NX; i += TPB) a += woutrow[i] * xc[i];
            for (int off = 32; off; off >>= 1) a += __shfl_down(a, off, 64);
            if ((tid & 63) == 0) red[tid >> 6] = a;
            __syncthreads();
            if (tid == 0) {
                float s = 0.0f;
                #pragma unroll
                for (int i = 0; i < TPB / 64; ++i) s += red[i];
                Y[(size_t)(t - 1) * NY + wg] = s;
            }
        }
    }

    // ---- final: stage x_T (epoch TSTEPS, slot 0) and emit Y[T-1] ----
    {
        float* xc = xl[0];
        stage_state(xbuf + (size_t)(TSTEPS & 1) * NX, xc, tid, (unsigned)TSTEPS);
        float a = 0.0f;
        for (int i = tid; i < NX; i += TPB) a += woutrow[i] * xc[i];
        for (int off = 32; off; off >>= 1) a += __shfl_down(a, off, 64);
        if ((tid & 63) == 0) red[tid >> 6] = a;
        __syncthreads();
        if (tid == 0) {
            float s = 0.0f;
            #pragma unroll
            for (int i = 0; i < TPB / 64; ++i) s += red[i];
            Y[(size_t)(TSTEPS - 1) * NY + wg] = s;
        }
    }
}

extern "C" void kernel_launch(void* const* d_in, const int* in_sizes, int n_in,
                              void* d_out, int out_size, void* d_ws, size_t ws_size,
                              hipStream_t stream) {
    const float* UT   = (const float*)d_in[0];  // [T, NU]
    const float* x0   = (const float*)d_in[1];  // [NX]
    const float* Win  = (const float*)d_in[2];  // [NX, NU]
    const float* W    = (const float*)d_in[3];  // [NX, NX]
    const float* Wout = (const float*)d_in[4];  // [NY, NX]
    float* Y = (float*)d_out;                   // [T*NY]

    char* ws = (char*)d_ws;
    u64*  xbuf = (u64*)ws;                      // 2*NX packed words = 64 KB
    int2* ell  = (int2*)(ws + 65536);           // NX*CAP*8 = 11,534,336 B

    build_ell_kernel<<<dim3(NX), dim3(256), 0, stream>>>(W, ell);

    void* args[] = { (void*)&UT, (void*)&x0, (void*)&Win, (void*)&Wout,
                     (void*)&ell, (void*)&xbuf, (void*)&Y };
    hipLaunchCooperativeKernel((const void*)esn_kernel, dim3(WGS), dim3(TPB),
                               args, 0, stream);
}

// Round 7
// 22744.466 us; speedup vs baseline: 3.4511x; 3.4511x over previous
//
#include <hip/hip_runtime.h>
#include <math.h>

// ESN forward: x_{t+1} = 0.1*x_t + 0.9*tanh(W_in @ u_t + W @ x_t); y_t = Wout @ x_{t+1}
// W sparse (5%) -> padded ELL in ws. 64 cooperative WGs x 512, fence-free.
// R7: - ELL loads back inline (R6's reg-prefetch spilled to scratch: 43GB writes)
//     - reader-major flag matrix flags[reader][writer]: each WG polls its own
//       PRIVATE 64-int row (coalesced, no cross-WG hot lines). Writers scatter
//       epoch to 64 rows after data is at the coherence point (vmcnt(0)+barrier).
//     - plain fp32 payload, no tags/retry; parity double-buffer is safe.

#define NX 4096
#define NU 128
#define NY 64
#define TSTEPS 4096
#define CAP 352            // padded nnz per row (mean 204.8, sd 13.9)
#define WGS 64
#define TPB 512
#define RPW (NX / WGS)     // 64 rows per workgroup
#define TPR (TPB / RPW)    // 8 threads per row
#define EPT (CAP / TPR)    // 44 ELL entries per thread -> 22 int4
#define UPT (NU / TPR)     // 16 W_in entries per thread
#define XW  (NX / 2 / TPB) // 4 u64 bulk words per thread

typedef unsigned long long u64;

// --- Kernel 1: dense->ELL compaction (one block per row) + flag init ---
__global__ void build_ell_kernel(const float* __restrict__ W, int2* __restrict__ ell,
                                 int* __restrict__ flags) {
    const int r = blockIdx.x;
    const int tid = threadIdx.x;
    if (r == 0)
        for (int i = tid; i < WGS * WGS; i += 256) flags[i] = 0;
    const int wv = tid >> 6, ln = tid & 63;
    __shared__ int wave_tot[4];
    __shared__ int base;
    if (tid == 0) base = 0;
    __syncthreads();
    const float* row = W + (size_t)r * NX;
    int2* out = ell + (size_t)r * CAP;
    for (int chunk = 0; chunk < NX; chunk += 256) {
        float w = row[chunk + tid];
        bool p = (w != 0.0f);
        unsigned long long m = __ballot(p);
        int lp = (int)__popcll(m & ((1ull << ln) - 1ull));
        if (ln == 63) wave_tot[wv] = lp + (p ? 1 : 0);
        __syncthreads();
        int wbase = 0;
        #pragma unroll
        for (int i = 0; i < 4; ++i)
            if (i < wv) wbase += wave_tot[i];
        int tot = wave_tot[0] + wave_tot[1] + wave_tot[2] + wave_tot[3];
        if (p) {
            int o = base + wbase + lp;
            if (o < CAP) out[o] = make_int2(chunk + tid, __float_as_int(w));
        }
        __syncthreads();
        if (tid == 0) base += tot;
        __syncthreads();
    }
    for (int o = base + tid; o < CAP; o += 256) out[o] = make_int2(0, 0);
}

__device__ __forceinline__ u64 ld_agent64(const u64* p) {
    return __hip_atomic_load(p, __ATOMIC_RELAXED, __HIP_MEMORY_SCOPE_AGENT);
}

// --- Kernel 2: cooperative sequential recurrence ---
__global__ void __launch_bounds__(TPB, 1) esn_kernel(
    const float* __restrict__ UT, const float* __restrict__ x0,
    const float* __restrict__ Win, const float* __restrict__ Wout,
    const int2* __restrict__ ell, float* __restrict__ xbuf,  // [2][NX] fp32
    int* __restrict__ flags,                                  // [64][64]
    float* __restrict__ Y)
{
    __shared__ __align__(16) float xl[2][NX];
    __shared__ float red[TPB / 64];

    const int tid = threadIdx.x;
    const int wg  = blockIdx.x;              // 0..63
    const int grp = tid >> 3;                // row group within WG (0..63)
    const int ln  = tid & 7;                 // lane within row group
    const int r   = wg * RPW + grp;          // global row this 8-thread group owns

    const float4* winrow = (const float4*)(Win + (size_t)r * NU + ln * UPT);
    const int4*   ellrow = (const int4*)  (ell + (size_t)r * CAP + ln * EPT);
    const float*  woutrow = Wout + (size_t)wg * NX;
    int* myflags = flags + wg * WGS;         // private poll row (reader-major)

    for (int t = 0; t < TSTEPS; ++t) {
        float* xc = xl[t & 1];

        // ---- x-independent partial: acc = Win[r,:] @ u_t ----
        float acc = 0.0f;
        {
            const float4* u4 = (const float4*)(UT + (size_t)t * NU + ln * UPT);
            #pragma unroll
            for (int i = 0; i < UPT / 4; ++i) {
                float4 w = winrow[i], u = u4[i];
                acc += w.x * u.x + w.y * u.y + w.z * u.z + w.w * u.w;
            }
        }

        // ---- stage x_t into LDS ----
        if (t == 0) {
            const float4* xs4 = (const float4*)x0;
            float4* xl4 = (float4*)xc;
            #pragma unroll
            for (int i = tid; i < NX / 4; i += TPB) xl4[i] = xs4[i];
            __syncthreads();
        } else {
            // detect: wave 0 polls its PRIVATE flag row (coalesced, uncontended)
            if (tid < 64) {
                int v;
                do {
                    v = __hip_atomic_load(myflags + tid, __ATOMIC_RELAXED,
                                          __HIP_MEMORY_SCOPE_AGENT);
                } while (__ballot(v < t) != 0ull);
            }
            __syncthreads();
            // bulk load x_t (flags guarantee visibility; no tags needed)
            const u64* xs = (const u64*)(xbuf + (size_t)(t & 1) * NX);
            u64 v[XW];
            #pragma unroll
            for (int j = 0; j < XW; ++j) v[j] = ld_agent64(xs + tid + TPB * j);
            u64* xc8 = (u64*)xc;
            #pragma unroll
            for (int j = 0; j < XW; ++j) xc8[tid + TPB * j] = v[j];
            __syncthreads();
        }

        // ---- acc += W[r,:] @ x_t (ELL int4 stream from L2, gather from LDS) ----
        #pragma unroll 4
        for (int i = 0; i < EPT / 2; ++i) {
            int4 cv = ellrow[i];   // two (col,val) pairs
            acc += __int_as_float(cv.y) * xc[cv.x]
                 + __int_as_float(cv.w) * xc[cv.z];
        }
        acc += __shfl_down(acc, 4, 8);
        acc += __shfl_down(acc, 2, 8);
        acc += __shfl_down(acc, 1, 8);

        // ---- publish x_{t+1} (per-row sc1 store), release, then flag scatter ----
        if (ln == 0) {
            float xn = 0.1f * xc[r] + 0.9f * tanhf(acc);
            __hip_atomic_store(xbuf + (size_t)((t + 1) & 1) * NX + r, xn,
                               __ATOMIC_RELAXED, __HIP_MEMORY_SCOPE_AGENT);
        }
        asm volatile("s_waitcnt vmcnt(0)" ::: "memory");  // this wave's stores acked
        __syncthreads();                                   // all waves' stores acked
        if (tid < 64)   // scatter epoch to every reader's private row
            __hip_atomic_store(flags + tid * WGS + wg, t + 1,
                               __ATOMIC_RELAXED, __HIP_MEMORY_SCOPE_AGENT);

        // ---- readout Y[t-1] = Wout[wg] . x_t (hidden in others' wait window) ----
        if (t > 0) {
            float a = 0.0f;
            for (int i = tid; i < NX; i += TPB) a += woutrow[i] * xc[i];
            for (int off = 32; off; off >>= 1) a += __shfl_down(a, off, 64);
            if ((tid & 63) == 0) red[tid >> 6] = a;
            __syncthreads();
            if (tid == 0) {
                float s = 0.0f;
                #pragma unroll
                for (int i = 0; i < TPB / 64; ++i) s += red[i];
                Y[(size_t)(t - 1) * NY + wg] = s;
            }
        }
    }

    // ---- final: stage x_T (slot 0) and emit Y[T-1] ----
    {
        float* xc = xl[0];
        if (tid < 64) {
            int v;
            do {
                v = __hip_atomic_load(myflags + tid, __ATOMIC_RELAXED,
                                      __HIP_MEMORY_SCOPE_AGENT);
            } while (__ballot(v < TSTEPS) != 0ull);
        }
        __syncthreads();
        const u64* xs = (const u64*)(xbuf + (size_t)(TSTEPS & 1) * NX);
        u64 v[XW];
        #pragma unroll
        for (int j = 0; j < XW; ++j) v[j] = ld_agent64(xs + tid + TPB * j);
        u64* xc8 = (u64*)xc;
        #pragma unroll
        for (int j = 0; j < XW; ++j) xc8[tid + TPB * j] = v[j];
        __syncthreads();

        float a = 0.0f;
        for (int i = tid; i < NX; i += TPB) a += woutrow[i] * xc[i];
        for (int off = 32; off; off >>= 1) a += __shfl_down(a, off, 64);
        if ((tid & 63) == 0) red[tid >> 6] = a;
        __syncthreads();
        if (tid == 0) {
            float s = 0.0f;
            #pragma unroll
            for (int i = 0; i < TPB / 64; ++i) s += red[i];
            Y[(size_t)(TSTEPS - 1) * NY + wg] = s;
        }
    }
}

extern "C" void kernel_launch(void* const* d_in, const int* in_sizes, int n_in,
                              void* d_out, int out_size, void* d_ws, size_t ws_size,
                              hipStream_t stream) {
    const float* UT   = (const float*)d_in[0];  // [T, NU]
    const float* x0   = (const float*)d_in[1];  // [NX]
    const float* Win  = (const float*)d_in[2];  // [NX, NU]
    const float* W    = (const float*)d_in[3];  // [NX, NX]
    const float* Wout = (const float*)d_in[4];  // [NY, NX]
    float* Y = (float*)d_out;                   // [T*NY]

    char* ws = (char*)d_ws;
    float* xbuf  = (float*)ws;                  // 2*NX fp32 = 32 KB
    int*   flags = (int*)(ws + 32768);          // 64*64 ints = 16 KB
    int2*  ell   = (int2*)(ws + 49152);         // NX*CAP*8 = 11,534,336 B

    build_ell_kernel<<<dim3(NX), dim3(256), 0, stream>>>(W, ell, flags);

    void* args[] = { (void*)&UT, (void*)&x0, (void*)&Win, (void*)&Wout,
                     (void*)&ell, (void*)&xbuf, (void*)&flags, (void*)&Y };
    hipLaunchCooperativeKernel((const void*)esn_kernel, dim3(WGS), dim3(TPB),
                               args, 0, stream);
}